// Round 4
// baseline (298.713 us; speedup 1.0000x reference)
//
#include <hip/hip_runtime.h>
#include <hip/hip_bf16.h>
#include <stdint.h>

typedef __attribute__((ext_vector_type(8))) short short8;
typedef __attribute__((ext_vector_type(4))) float f32x4;

#define ROWLEN 8704   // 17*512

__device__ __forceinline__ unsigned short f2bf(float f) {
    union { float f; unsigned int u; } v; v.f = f;
    unsigned int r = v.u + 0x7fffu + ((v.u >> 16) & 1u);   // round-nearest-even
    return (unsigned short)(r >> 16);
}
__device__ __forceinline__ unsigned int pk2(unsigned short a, unsigned short b) {
    return (unsigned int)a | ((unsigned int)b << 16);
}
__device__ __forceinline__ float silu_f(float x) {
    return x / (1.0f + __expf(-x));
}
__device__ __forceinline__ float sel3(float a, float b, float c, int o) {
    float r = (o == 1) ? b : a;
    return (o == 2) ? c : r;
}

// ---------------------------------------------------------------------------
// Kernel 1: bid 0        : L = I - D^-1/2 A D^-1/2  -> Lw[289]
//           bid [1,129)  : transpose-cast W_mod [512][1024] f32 -> wbT [1024][512] bf16
//           bid [129,1153): cb[b][c] = bf16(silu(c_in[b][c]))
// ---------------------------------------------------------------------------
__global__ __launch_bounds__(256) void prep_kernel(
        const float* __restrict__ cin, const float* __restrict__ Wmod,
        const float* __restrict__ adj,
        unsigned short* __restrict__ cb, unsigned short* __restrict__ wbT,
        float* __restrict__ Lw) {
    int bid = blockIdx.x;
    int tid = threadIdx.x;
    if (bid == 0) {
        __shared__ float dsh[17];
        if (tid < 17) {
            float rs = 0.0f;
            #pragma unroll
            for (int j = 0; j < 17; ++j) rs += adj[tid * 17 + j];
            dsh[tid] = rsqrtf(rs);
        }
        __syncthreads();
        for (int e = tid; e < 289; e += 256) {
            int i = e / 17, j = e - i * 17;
            Lw[e] = (i == j ? 1.0f : 0.0f) - dsh[i] * adj[e] * dsh[j];
        }
    } else if (bid < 129) {
        __shared__ float tile[64][65];
        int bt = bid - 1;
        int txt = bt & 15, tyt = bt >> 4;
        int cx = tid & 63, ry = tid >> 6;
        #pragma unroll
        for (int rr = 0; rr < 16; ++rr) {
            int r = ry + rr * 4;
            tile[r][cx] = Wmod[(tyt*64 + r) * 1024 + txt*64 + cx];
        }
        __syncthreads();
        #pragma unroll
        for (int rr = 0; rr < 16; ++rr) {
            int r = ry + rr * 4;
            wbT[(txt*64 + r) * 512 + tyt*64 + cx] = f2bf(tile[cx][r]);
        }
    } else {
        int t = (bid - 129) * 256 + tid;
        const float4* s = reinterpret_cast<const float4*>(cin) + (size_t)t * 2;
        float4 a = s[0], b = s[1];
        uint4 o;
        o.x = pk2(f2bf(silu_f(a.x)), f2bf(silu_f(a.y)));
        o.y = pk2(f2bf(silu_f(a.z)), f2bf(silu_f(a.w)));
        o.z = pk2(f2bf(silu_f(b.x)), f2bf(silu_f(b.y)));
        o.w = pk2(f2bf(silu_f(b.z)), f2bf(silu_f(b.w)));
        *reinterpret_cast<uint4*>(cb + (size_t)t * 8) = o;
    }
}

// ---------------------------------------------------------------------------
// Kernel 2: H[4096][1024] = cb[4096][512] @ wbT^T + b_mod   (MFMA bf16)
// ---------------------------------------------------------------------------
__global__ __launch_bounds__(256) void gemm_kernel(
        const unsigned short* __restrict__ cb, const unsigned short* __restrict__ wbT,
        const float* __restrict__ b_mod, float* __restrict__ H) {
    int w = threadIdx.x >> 6, l = threadIdx.x & 63;
    int lr = l & 15, lk = (l >> 4) * 8;
    int rowbase = blockIdx.y * 128 + w * 32;
    int colbase = blockIdx.x * 64;
    f32x4 acc[2][4] = {};
    for (int kk = 0; kk < 16; ++kk) {
        int k = kk * 32 + lk;
        short8 a0 = *reinterpret_cast<const short8*>(cb + (size_t)(rowbase + lr) * 512 + k);
        short8 a1 = *reinterpret_cast<const short8*>(cb + (size_t)(rowbase + 16 + lr) * 512 + k);
        #pragma unroll
        for (int j = 0; j < 4; ++j) {
            short8 bv = *reinterpret_cast<const short8*>(wbT + (size_t)(colbase + j*16 + lr) * 512 + k);
            acc[0][j] = __builtin_amdgcn_mfma_f32_16x16x32_bf16(a0, bv, acc[0][j], 0, 0, 0);
            acc[1][j] = __builtin_amdgcn_mfma_f32_16x16x32_bf16(a1, bv, acc[1][j], 0, 0, 0);
        }
    }
    #pragma unroll
    for (int j = 0; j < 4; ++j) {
        int col = colbase + j * 16 + lr;
        float bm = b_mod[col];
        #pragma unroll
        for (int i = 0; i < 2; ++i) {
            int row0 = rowbase + i * 16 + (l >> 4) * 4;
            #pragma unroll
            for (int r = 0; r < 4; ++r)
                H[(size_t)(row0 + r) * 1024 + col] = acc[i][j][r] + bm;
        }
    }
}

// ---------------------------------------------------------------------------
// Kernel 3 (mainA): streaming MFMA over flattened rows g = b*17 + n.
// 8 waves x 16 rows = 128 rows/block, grid 544. Single pass over x:
//   G[g][o] = sum_c bf16(x_c*(1+scale_bc)) * bf16(Wg[c][o])   (MFMA, all waves)
//   + per-row sum/sumsq (raw x) -> mu, rstd.  LN applied later:
//   P = rstd*(G - mu*CS) in the combine kernel.
// Writes Gw[g][12]: cols 0-8 = G, 9 = mu, 10 = rstd.
// ---------------------------------------------------------------------------
__global__ __launch_bounds__(512, 3) void mainA_kernel(
        const float* __restrict__ x, const float* __restrict__ Wg,
        const float* __restrict__ H, float* __restrict__ Gw) {
    __shared__ float scl[9][520];      // (1+scale) for the block's <=9 batches

    int tid = threadIdx.x, w = tid >> 6, l = tid & 63;
    int R0 = blockIdx.x * 128;
    int b_lo = R0 / 17;

    #pragma unroll
    for (int bi = 0; bi < 9; ++bi) {
        int b = b_lo + bi; if (b > 4095) b = 4095;
        scl[bi][tid] = 1.0f + H[(size_t)b * 1024 + 512 + tid];
    }

    // B-fragment preload: lane col = l&15 (output o-index), k-chunk q = l>>4
    int col = l & 15, q = l >> 4;
    bool bvalid = col < 9;
    int cheb = col / 3, oo = col - cheb * 3;
    const float* wgbase = Wg + cheb * 1536 + oo;
    short8 bf[16];
    #pragma unroll
    for (int kk = 0; kk < 16; ++kk) {
        unsigned short t[8];
        #pragma unroll
        for (int j = 0; j < 8; ++j) {
            int c = kk * 32 + q * 8 + j;
            float v = bvalid ? wgbase[c * 3] : 0.0f;
            t[j] = f2bf(v);
        }
        uint4 uv;
        uv.x = pk2(t[0], t[1]); uv.y = pk2(t[2], t[3]);
        uv.z = pk2(t[4], t[5]); uv.w = pk2(t[6], t[7]);
        bf[kk] = *reinterpret_cast<short8*>(&uv);
    }
    __syncthreads();

    // A side: lane's row = l&15 within the wave's 16-row group
    int myrow = R0 + w * 16 + col;           // col == l&15 doubles as A-row
    int bi = myrow / 17 - b_lo;
    const float* xrow = x + (size_t)myrow * 512 + q * 8;
    const float* srow = &scl[bi][q * 8];

    float sum = 0.0f, sumsq = 0.0f;
    f32x4 acc = {0.f, 0.f, 0.f, 0.f};
    #pragma unroll
    for (int kk = 0; kk < 16; ++kk) {
        float4 xa = *reinterpret_cast<const float4*>(xrow + kk * 32);
        float4 xb = *reinterpret_cast<const float4*>(xrow + kk * 32 + 4);
        float4 sa = *reinterpret_cast<const float4*>(srow + kk * 32);
        float4 sb = *reinterpret_cast<const float4*>(srow + kk * 32 + 4);
        sum  += xa.x + xa.y + xa.z + xa.w + xb.x + xb.y + xb.z + xb.w;
        sumsq = fmaf(xa.x, xa.x, sumsq); sumsq = fmaf(xa.y, xa.y, sumsq);
        sumsq = fmaf(xa.z, xa.z, sumsq); sumsq = fmaf(xa.w, xa.w, sumsq);
        sumsq = fmaf(xb.x, xb.x, sumsq); sumsq = fmaf(xb.y, xb.y, sumsq);
        sumsq = fmaf(xb.z, xb.z, sumsq); sumsq = fmaf(xb.w, xb.w, sumsq);
        uint4 uv;
        uv.x = pk2(f2bf(xa.x * sa.x), f2bf(xa.y * sa.y));
        uv.y = pk2(f2bf(xa.z * sa.z), f2bf(xa.w * sa.w));
        uv.z = pk2(f2bf(xb.x * sb.x), f2bf(xb.y * sb.y));
        uv.w = pk2(f2bf(xb.z * sb.z), f2bf(xb.w * sb.w));
        short8 av = *reinterpret_cast<short8*>(&uv);
        acc = __builtin_amdgcn_mfma_f32_16x16x32_bf16(av, bf[kk], acc, 0, 0, 0);
    }

    // reduce raw-x stats across the 4 q-groups holding the same row
    sum   += __shfl_xor(sum, 16);   sum   += __shfl_xor(sum, 32);
    sumsq += __shfl_xor(sumsq, 16); sumsq += __shfl_xor(sumsq, 32);
    float mu  = sum * (1.0f / 512.0f);
    float var = sumsq * (1.0f / 512.0f) - mu * mu;
    float rstd = rsqrtf(var + 1e-6f);

    size_t gbase = (size_t)(R0 + w * 16);
    if (bvalid) {
        #pragma unroll
        for (int r = 0; r < 4; ++r)
            Gw[(gbase + q * 4 + r) * 12 + col] = acc[r];
    }
    if (l < 16) {
        Gw[(gbase + l) * 12 + 9]  = mu;
        Gw[(gbase + l) * 12 + 10] = rstd;
    }
}

// ---------------------------------------------------------------------------
// Kernel 4 (combine): per batch (wave): S = shift@Wt, CS = (1+scale)@Wt (f32,
// conflict-free element-transposed Wt in LDS), then P = rstd*(G - mu*CS),
// A_k = P_k + S_k, Q = L@A2, out = A0 - A2 + L@(A1 + 2Q) + bg.
// ---------------------------------------------------------------------------
__global__ __launch_bounds__(512) void combine_kernel(
        const float* __restrict__ H, const float* __restrict__ Wg,
        const float* __restrict__ Lw, const float* __restrict__ bg,
        const float* __restrict__ Gw, float* __restrict__ out) {
    __shared__ float Wt_t[9][512];     // [r][(c&7)*64 + (c>>3)]
    __shared__ float L_s[17][20];
    __shared__ float A2_s[8][17][3];
    __shared__ float B1_s[8][17][3];

    int tid = threadIdx.x, w = tid >> 6, l = tid & 63;

    #pragma unroll
    for (int r = 0; r < 9; ++r) {
        int c = tid;
        Wt_t[r][(c & 7) * 64 + (c >> 3)] = Wg[(r / 3) * 1536 + c * 3 + (r % 3)];
    }
    if (tid < 289) L_s[tid / 17][tid % 17] = Lw[tid];
    __syncthreads();

    int b = blockIdx.x * 8 + w;
    const float* hrow = H + (size_t)b * 1024;
    float4 h0 = *reinterpret_cast<const float4*>(hrow + 8 * l);
    float4 h1 = *reinterpret_cast<const float4*>(hrow + 8 * l + 4);
    float4 h2 = *reinterpret_cast<const float4*>(hrow + 512 + 8 * l);
    float4 h3 = *reinterpret_cast<const float4*>(hrow + 512 + 8 * l + 4);
    float shj[8] = {h0.x, h0.y, h0.z, h0.w, h1.x, h1.y, h1.z, h1.w};
    float scj[8] = {1.f+h2.x, 1.f+h2.y, 1.f+h2.z, 1.f+h2.w,
                    1.f+h3.x, 1.f+h3.y, 1.f+h3.z, 1.f+h3.w};

    float sA[9], cA[9];
    #pragma unroll
    for (int r = 0; r < 9; ++r) {
        float s = 0.0f, cs = 0.0f;
        #pragma unroll
        for (int j = 0; j < 8; ++j) {
            float wv = Wt_t[r][j * 64 + l];
            s  = fmaf(shj[j], wv, s);
            cs = fmaf(scj[j], wv, cs);
        }
        sA[r] = s; cA[r] = cs;
    }
    #pragma unroll
    for (int m = 1; m < 64; m <<= 1) {
        #pragma unroll
        for (int r = 0; r < 9; ++r) {
            sA[r] += __shfl_xor(sA[r], m);
            cA[r] += __shfl_xor(cA[r], m);
        }
    }

    int lc = l < 51 ? l : 50;
    int n = lc / 3, o = lc - n * 3;
    float S0 = sel3(sA[0], sA[1], sA[2], o);
    float S1 = sel3(sA[3], sA[4], sA[5], o);
    float S2 = sel3(sA[6], sA[7], sA[8], o);
    float C0 = sel3(cA[0], cA[1], cA[2], o);
    float C1 = sel3(cA[3], cA[4], cA[5], o);
    float C2 = sel3(cA[6], cA[7], cA[8], o);

    const float* grow = Gw + (size_t)(b * 17 + n) * 12;
    float g0 = grow[o], g1 = grow[3 + o], g2 = grow[6 + o];
    float mu = grow[9], rstd = grow[10];
    float A0 = rstd * (g0 - mu * C0) + S0;
    float A1 = rstd * (g1 - mu * C1) + S1;
    float A2 = rstd * (g2 - mu * C2) + S2;

    A2_s[w][n][o] = A2;
    __syncthreads();
    float Qv = 0.0f;
    #pragma unroll
    for (int m = 0; m < 17; ++m) Qv = fmaf(L_s[n][m], A2_s[w][m][o], Qv);
    B1_s[w][n][o] = A1 + 2.0f * Qv;
    __syncthreads();
    float rv = A0 - A2 + bg[o];
    #pragma unroll
    for (int m = 0; m < 17; ++m) rv = fmaf(L_s[n][m], B1_s[w][m][o], rv);
    if (l < 51) out[(size_t)b * 51 + lc] = rv;
}

// ---------------------------------------------------------------------------
extern "C" void kernel_launch(void* const* d_in, const int* in_sizes, int n_in,
                              void* d_out, int out_size, void* d_ws, size_t ws_size,
                              hipStream_t stream) {
    const float* x     = (const float*)d_in[0];
    const float* adj   = (const float*)d_in[1];
    const float* c     = (const float*)d_in[2];
    const float* W_mod = (const float*)d_in[3];
    const float* b_mod = (const float*)d_in[4];
    const float* Wg    = (const float*)d_in[5];
    const float* bg    = (const float*)d_in[6];
    float* out = (float*)d_out;

    // workspace: cb 4MB @0 | wbT 1MB @4MB | H 16MB @5MB | Lw @21MB | Gw @22MB
    unsigned short* cb  = (unsigned short*)d_ws;
    unsigned short* wbT = (unsigned short*)((char*)d_ws + (4u << 20));
    float*          H   = (float*)((char*)d_ws + (5u << 20));
    float*          Lw  = (float*)((char*)d_ws + (21u << 20));
    float*          Gw  = (float*)((char*)d_ws + (22u << 20));

    prep_kernel<<<1153, 256, 0, stream>>>(c, W_mod, adj, cb, wbT, Lw);
    gemm_kernel<<<dim3(16, 32), 256, 0, stream>>>(cb, wbT, b_mod, H);
    mainA_kernel<<<544, 512, 0, stream>>>(x, Wg, H, Gw);
    combine_kernel<<<512, 512, 0, stream>>>(H, Wg, Lw, bg, Gw, out);
}

// Round 7
// 263.179 us; speedup vs baseline: 1.1350x; 1.1350x over previous
//
#include <hip/hip_runtime.h>
#include <hip/hip_bf16.h>
#include <stdint.h>

typedef __attribute__((ext_vector_type(8))) short short8;
typedef __attribute__((ext_vector_type(4))) float f32x4;

#define ROWLEN 8704   // 17*512

__device__ __forceinline__ unsigned short f2bf(float f) {
    union { float f; unsigned int u; } v; v.f = f;
    unsigned int r = v.u + 0x7fffu + ((v.u >> 16) & 1u);   // round-nearest-even
    return (unsigned short)(r >> 16);
}
__device__ __forceinline__ unsigned int pk2(unsigned short a, unsigned short b) {
    return (unsigned int)a | ((unsigned int)b << 16);
}
__device__ __forceinline__ float silu_f(float x) {
    return x / (1.0f + __expf(-x));
}
__device__ __forceinline__ float sel3(float a, float b, float c, int o) {
    float r = (o == 1) ? b : a;
    return (o == 2) ? c : r;
}

// ---------------------------------------------------------------------------
// Kernel 1 (prep):
//  bid 0          : L = I - D^-1/2 A D^-1/2 -> Lw[289]
//  bid [1,129)    : transpose-cast W_mod -> wbT [1024][512] bf16
//  bid [129,1153) : cb = bf16(silu(c_in))
//  bid [1153,1169): wgb = per-lane MFMA B-fragment image of Wg (16 kk-slabs)
//  bid 1169       : Wtg = swizzled f32 Wt table for combine
// ---------------------------------------------------------------------------
__global__ __launch_bounds__(256) void prep_kernel(
        const float* __restrict__ cin, const float* __restrict__ Wmod,
        const float* __restrict__ adj, const float* __restrict__ Wg,
        unsigned short* __restrict__ cb, unsigned short* __restrict__ wbT,
        float* __restrict__ Lw, unsigned short* __restrict__ wgb,
        float* __restrict__ Wtg) {
    int bid = blockIdx.x;
    int tid = threadIdx.x;
    if (bid == 0) {
        __shared__ float dsh[17];
        if (tid < 17) {
            float rs = 0.0f;
            #pragma unroll
            for (int j = 0; j < 17; ++j) rs += adj[tid * 17 + j];
            dsh[tid] = rsqrtf(rs);
        }
        __syncthreads();
        for (int e = tid; e < 289; e += 256) {
            int i = e / 17, j = e - i * 17;
            Lw[e] = (i == j ? 1.0f : 0.0f) - dsh[i] * adj[e] * dsh[j];
        }
    } else if (bid < 129) {
        __shared__ float tile[64][65];
        int bt = bid - 1;
        int txt = bt & 15, tyt = bt >> 4;
        int cx = tid & 63, ry = tid >> 6;
        #pragma unroll
        for (int rr = 0; rr < 16; ++rr) {
            int r = ry + rr * 4;
            tile[r][cx] = Wmod[(tyt*64 + r) * 1024 + txt*64 + cx];
        }
        __syncthreads();
        #pragma unroll
        for (int rr = 0; rr < 16; ++rr) {
            int r = ry + rr * 4;
            wbT[(txt*64 + r) * 512 + tyt*64 + cx] = f2bf(tile[cx][r]);
        }
    } else if (bid < 1153) {
        int t = (bid - 129) * 256 + tid;
        const float4* s = reinterpret_cast<const float4*>(cin) + (size_t)t * 2;
        float4 a = s[0], b = s[1];
        uint4 o;
        o.x = pk2(f2bf(silu_f(a.x)), f2bf(silu_f(a.y)));
        o.y = pk2(f2bf(silu_f(a.z)), f2bf(silu_f(a.w)));
        o.z = pk2(f2bf(silu_f(b.x)), f2bf(silu_f(b.y)));
        o.w = pk2(f2bf(silu_f(b.z)), f2bf(silu_f(b.w)));
        *reinterpret_cast<uint4*>(cb + (size_t)t * 8) = o;
    } else if (bid < 1169) {
        // wgb[(kk*64 + l)*8 .. +7] = bf16 B-fragment (lane l, k-slab kk)
        int kk = bid - 1153;
        if (tid < 64) {
            int l = tid;
            int col = l & 15, q = l >> 4;
            bool bvalid = col < 9;
            int cheb = col / 3, oo = col - cheb * 3;
            unsigned short t[8];
            #pragma unroll
            for (int j = 0; j < 8; ++j) {
                int c = kk * 32 + q * 8 + j;
                float v = bvalid ? Wg[cheb * 1536 + c * 3 + oo] : 0.0f;
                t[j] = f2bf(v);
            }
            uint4 uv;
            uv.x = pk2(t[0], t[1]); uv.y = pk2(t[2], t[3]);
            uv.z = pk2(t[4], t[5]); uv.w = pk2(t[6], t[7]);
            *reinterpret_cast<uint4*>(wgb + ((size_t)kk * 64 + l) * 8) = uv;
        }
    } else {
        // Wtg[r*512 + i] with i = (c&7)*64 + (c>>3)  ->  c = ((i&63)<<3) | (i>>6)
        for (int idx = tid; idx < 4608; idx += 256) {
            int r = idx >> 9, i = idx & 511;
            int c = ((i & 63) << 3) | (i >> 6);
            Wtg[idx] = Wg[(r / 3) * 1536 + c * 3 + (r % 3)];
        }
    }
}

// ---------------------------------------------------------------------------
// Kernel 2: H[4096][1024] = cb[4096][512] @ wbT^T + b_mod   (MFMA bf16)
// ---------------------------------------------------------------------------
__global__ __launch_bounds__(256) void gemm_kernel(
        const unsigned short* __restrict__ cb, const unsigned short* __restrict__ wbT,
        const float* __restrict__ b_mod, float* __restrict__ H) {
    int w = threadIdx.x >> 6, l = threadIdx.x & 63;
    int lr = l & 15, lk = (l >> 4) * 8;
    int rowbase = blockIdx.y * 128 + w * 32;
    int colbase = blockIdx.x * 64;
    f32x4 acc[2][4] = {};
    for (int kk = 0; kk < 16; ++kk) {
        int k = kk * 32 + lk;
        short8 a0 = *reinterpret_cast<const short8*>(cb + (size_t)(rowbase + lr) * 512 + k);
        short8 a1 = *reinterpret_cast<const short8*>(cb + (size_t)(rowbase + 16 + lr) * 512 + k);
        #pragma unroll
        for (int j = 0; j < 4; ++j) {
            short8 bv = *reinterpret_cast<const short8*>(wbT + (size_t)(colbase + j*16 + lr) * 512 + k);
            acc[0][j] = __builtin_amdgcn_mfma_f32_16x16x32_bf16(a0, bv, acc[0][j], 0, 0, 0);
            acc[1][j] = __builtin_amdgcn_mfma_f32_16x16x32_bf16(a1, bv, acc[1][j], 0, 0, 0);
        }
    }
    #pragma unroll
    for (int j = 0; j < 4; ++j) {
        int col = colbase + j * 16 + lr;
        float bm = b_mod[col];
        #pragma unroll
        for (int i = 0; i < 2; ++i) {
            int row0 = rowbase + i * 16 + (l >> 4) * 4;
            #pragma unroll
            for (int r = 0; r < 4; ++r)
                H[(size_t)(row0 + r) * 1024 + col] = acc[i][j][r] + bm;
        }
    }
}

// ---------------------------------------------------------------------------
// Kernel 3 (mainA): streaming MFMA over flattened rows g = b*17 + n.
// 4 waves x 16 rows = 64 rows/block, grid 1088. No LDS, no barrier.
// B-frags: 16 coalesced 16B loads from precomputed wgb.
// scale: direct float4 loads from H (L2/L3-resident, line-shared).
// Writes Gw[g][12]: cols 0-8 = G, 9 = mu, 10 = rstd.
// ---------------------------------------------------------------------------
__global__ __launch_bounds__(256, 4) void mainA_kernel(
        const float* __restrict__ x, const unsigned short* __restrict__ wgb,
        const float* __restrict__ H, float* __restrict__ Gw) {
    int tid = threadIdx.x, w = tid >> 6, l = tid & 63;
    int col = l & 15, q = l >> 4;
    int R0 = blockIdx.x * 64;
    int myrow = R0 + w * 16 + col;
    int b = myrow / 17;
    const float* xrow = x + (size_t)myrow * 512 + q * 8;
    const float* srow = H + (size_t)b * 1024 + 512 + q * 8;

    short8 bf[16];
    #pragma unroll
    for (int kk = 0; kk < 16; ++kk)
        bf[kk] = *reinterpret_cast<const short8*>(wgb + ((size_t)kk * 64 + l) * 8);

    float sum = 0.0f, sumsq = 0.0f;
    f32x4 acc = {0.f, 0.f, 0.f, 0.f};
    #pragma unroll
    for (int kk = 0; kk < 16; ++kk) {
        float4 xa = *reinterpret_cast<const float4*>(xrow + kk * 32);
        float4 xb = *reinterpret_cast<const float4*>(xrow + kk * 32 + 4);
        float4 sa = *reinterpret_cast<const float4*>(srow + kk * 32);
        float4 sb = *reinterpret_cast<const float4*>(srow + kk * 32 + 4);
        sum  += xa.x + xa.y + xa.z + xa.w + xb.x + xb.y + xb.z + xb.w;
        sumsq = fmaf(xa.x, xa.x, sumsq); sumsq = fmaf(xa.y, xa.y, sumsq);
        sumsq = fmaf(xa.z, xa.z, sumsq); sumsq = fmaf(xa.w, xa.w, sumsq);
        sumsq = fmaf(xb.x, xb.x, sumsq); sumsq = fmaf(xb.y, xb.y, sumsq);
        sumsq = fmaf(xb.z, xb.z, sumsq); sumsq = fmaf(xb.w, xb.w, sumsq);
        uint4 uv;
        uv.x = pk2(f2bf(xa.x * (1.0f + sa.x)), f2bf(xa.y * (1.0f + sa.y)));
        uv.y = pk2(f2bf(xa.z * (1.0f + sa.z)), f2bf(xa.w * (1.0f + sa.w)));
        uv.z = pk2(f2bf(xb.x * (1.0f + sb.x)), f2bf(xb.y * (1.0f + sb.y)));
        uv.w = pk2(f2bf(xb.z * (1.0f + sb.z)), f2bf(xb.w * (1.0f + sb.w)));
        short8 av = *reinterpret_cast<short8*>(&uv);
        acc = __builtin_amdgcn_mfma_f32_16x16x32_bf16(av, bf[kk], acc, 0, 0, 0);
    }

    // combine raw-x stats across the 4 q-groups holding the same row
    sum   += __shfl_xor(sum, 16);   sum   += __shfl_xor(sum, 32);
    sumsq += __shfl_xor(sumsq, 16); sumsq += __shfl_xor(sumsq, 32);
    float mu  = sum * (1.0f / 512.0f);
    float var = sumsq * (1.0f / 512.0f) - mu * mu;
    float rstd = rsqrtf(var + 1e-6f);

    size_t gbase = (size_t)(R0 + w * 16);
    if (col < 9) {
        #pragma unroll
        for (int r = 0; r < 4; ++r)
            Gw[(gbase + q * 4 + r) * 12 + col] = acc[r];
    }
    if (l < 16) {
        Gw[(gbase + l) * 12 + 9]  = mu;
        Gw[(gbase + l) * 12 + 10] = rstd;
    }
}

// ---------------------------------------------------------------------------
// Kernel 4 (combine): per batch (wave): S = shift@Wt, CS = (1+scale)@Wt,
// P = rstd*(G - mu*CS), A_k = P_k + S_k, Q = L@A2,
// out = A0 - A2 + L@(A1 + 2Q) + bg.
// ---------------------------------------------------------------------------
__global__ __launch_bounds__(512) void combine_kernel(
        const float* __restrict__ H, const float* __restrict__ Wtg,
        const float* __restrict__ Lw, const float* __restrict__ bg,
        const float* __restrict__ Gw, float* __restrict__ out) {
    __shared__ float Wt_t[9][512];     // pre-swizzled: row r, slot (c&7)*64+(c>>3)
    __shared__ float L_s[17][20];
    __shared__ float A2_s[8][17][3];
    __shared__ float B1_s[8][17][3];

    int tid = threadIdx.x, w = tid >> 6, l = tid & 63;

    #pragma unroll
    for (int r = 0; r < 9; ++r)
        Wt_t[r][tid] = Wtg[r * 512 + tid];
    if (tid < 289) L_s[tid / 17][tid % 17] = Lw[tid];
    __syncthreads();

    int b = blockIdx.x * 8 + w;
    const float* hrow = H + (size_t)b * 1024;
    float4 h0 = *reinterpret_cast<const float4*>(hrow + 8 * l);
    float4 h1 = *reinterpret_cast<const float4*>(hrow + 8 * l + 4);
    float4 h2 = *reinterpret_cast<const float4*>(hrow + 512 + 8 * l);
    float4 h3 = *reinterpret_cast<const float4*>(hrow + 512 + 8 * l + 4);
    float shj[8] = {h0.x, h0.y, h0.z, h0.w, h1.x, h1.y, h1.z, h1.w};
    float scj[8] = {1.f+h2.x, 1.f+h2.y, 1.f+h2.z, 1.f+h2.w,
                    1.f+h3.x, 1.f+h3.y, 1.f+h3.z, 1.f+h3.w};

    float sA[9], cA[9];
    #pragma unroll
    for (int r = 0; r < 9; ++r) {
        float s = 0.0f, cs = 0.0f;
        #pragma unroll
        for (int j = 0; j < 8; ++j) {
            float wv = Wt_t[r][j * 64 + l];
            s  = fmaf(shj[j], wv, s);
            cs = fmaf(scj[j], wv, cs);
        }
        sA[r] = s; cA[r] = cs;
    }
    #pragma unroll
    for (int m = 1; m < 64; m <<= 1) {
        #pragma unroll
        for (int r = 0; r < 9; ++r) {
            sA[r] += __shfl_xor(sA[r], m);
            cA[r] += __shfl_xor(cA[r], m);
        }
    }

    int lc = l < 51 ? l : 50;
    int n = lc / 3, o = lc - n * 3;
    float S0 = sel3(sA[0], sA[1], sA[2], o);
    float S1 = sel3(sA[3], sA[4], sA[5], o);
    float S2 = sel3(sA[6], sA[7], sA[8], o);
    float C0 = sel3(cA[0], cA[1], cA[2], o);
    float C1 = sel3(cA[3], cA[4], cA[5], o);
    float C2 = sel3(cA[6], cA[7], cA[8], o);

    const float* grow = Gw + (size_t)(b * 17 + n) * 12;
    float g0 = grow[o], g1 = grow[3 + o], g2 = grow[6 + o];
    float mu = grow[9], rstd = grow[10];
    float A0 = rstd * (g0 - mu * C0) + S0;
    float A1 = rstd * (g1 - mu * C1) + S1;
    float A2 = rstd * (g2 - mu * C2) + S2;

    A2_s[w][n][o] = A2;
    __syncthreads();
    float Qv = 0.0f;
    #pragma unroll
    for (int m = 0; m < 17; ++m) Qv = fmaf(L_s[n][m], A2_s[w][m][o], Qv);
    B1_s[w][n][o] = A1 + 2.0f * Qv;
    __syncthreads();
    float rv = A0 - A2 + bg[o];
    #pragma unroll
    for (int m = 0; m < 17; ++m) rv = fmaf(L_s[n][m], B1_s[w][m][o], rv);
    if (l < 51) out[(size_t)b * 51 + lc] = rv;
}

// ---------------------------------------------------------------------------
extern "C" void kernel_launch(void* const* d_in, const int* in_sizes, int n_in,
                              void* d_out, int out_size, void* d_ws, size_t ws_size,
                              hipStream_t stream) {
    const float* x     = (const float*)d_in[0];
    const float* adj   = (const float*)d_in[1];
    const float* c     = (const float*)d_in[2];
    const float* W_mod = (const float*)d_in[3];
    const float* b_mod = (const float*)d_in[4];
    const float* Wg    = (const float*)d_in[5];
    const float* bg    = (const float*)d_in[6];
    float* out = (float*)d_out;

    // workspace: cb 4MB @0 | wbT @4MB | H @5MB | Lw @21MB | Gw @22MB (3.3MB)
    //            wgb @32MB (16KB) | Wtg @33MB (18KB)     (d_ws is ~544MB)
    unsigned short* cb  = (unsigned short*)d_ws;
    unsigned short* wbT = (unsigned short*)((char*)d_ws + (4u << 20));
    float*          H   = (float*)((char*)d_ws + (5u << 20));
    float*          Lw  = (float*)((char*)d_ws + (21u << 20));
    float*          Gw  = (float*)((char*)d_ws + (22u << 20));
    unsigned short* wgb = (unsigned short*)((char*)d_ws + (32u << 20));
    float*          Wtg = (float*)((char*)d_ws + (33u << 20));

    prep_kernel<<<1170, 256, 0, stream>>>(c, W_mod, adj, Wg, cb, wbT, Lw, wgb, Wtg);
    gemm_kernel<<<dim3(16, 32), 256, 0, stream>>>(cb, wbT, b_mod, H);
    mainA_kernel<<<1088, 256, 0, stream>>>(x, wgb, H, Gw);
    combine_kernel<<<512, 512, 0, stream>>>(H, Wtg, Lw, bg, Gw, out);
}

// Round 8
// 260.312 us; speedup vs baseline: 1.1475x; 1.0110x over previous
//
#include <hip/hip_runtime.h>
#include <hip/hip_bf16.h>
#include <stdint.h>

typedef __attribute__((ext_vector_type(8))) short short8;
typedef __attribute__((ext_vector_type(4))) float f32x4;

#define ROWLEN 8704   // 17*512

__device__ __forceinline__ unsigned short f2bf(float f) {
    union { float f; unsigned int u; } v; v.f = f;
    unsigned int r = v.u + 0x7fffu + ((v.u >> 16) & 1u);   // round-nearest-even
    return (unsigned short)(r >> 16);
}
__device__ __forceinline__ unsigned int pk2(unsigned short a, unsigned short b) {
    return (unsigned int)a | ((unsigned int)b << 16);
}
__device__ __forceinline__ float silu_f(float x) {
    return x / (1.0f + __expf(-x));
}
__device__ __forceinline__ float sel3(float a, float b, float c, int o) {
    float r = (o == 1) ? b : a;
    return (o == 2) ? c : r;
}

// ---------------------------------------------------------------------------
// Kernel 1 (prep):
//  bid 0          : L = I - D^-1/2 A D^-1/2 -> Lw[289]
//  bid [1,129)    : transpose-cast W_mod -> wbT [1024][512] bf16
//  bid [129,1153) : cb = bf16(silu(c_in))
//  bid [1153,1169): wgb = per-lane MFMA B-fragment image of Wg (16 kk-slabs)
//  bid 1169       : Wtg = swizzled f32 Wt table for combine
// ---------------------------------------------------------------------------
__global__ __launch_bounds__(256) void prep_kernel(
        const float* __restrict__ cin, const float* __restrict__ Wmod,
        const float* __restrict__ adj, const float* __restrict__ Wg,
        unsigned short* __restrict__ cb, unsigned short* __restrict__ wbT,
        float* __restrict__ Lw, unsigned short* __restrict__ wgb,
        float* __restrict__ Wtg) {
    int bid = blockIdx.x;
    int tid = threadIdx.x;
    if (bid == 0) {
        __shared__ float dsh[17];
        if (tid < 17) {
            float rs = 0.0f;
            #pragma unroll
            for (int j = 0; j < 17; ++j) rs += adj[tid * 17 + j];
            dsh[tid] = rsqrtf(rs);
        }
        __syncthreads();
        for (int e = tid; e < 289; e += 256) {
            int i = e / 17, j = e - i * 17;
            Lw[e] = (i == j ? 1.0f : 0.0f) - dsh[i] * adj[e] * dsh[j];
        }
    } else if (bid < 129) {
        __shared__ float tile[64][65];
        int bt = bid - 1;
        int txt = bt & 15, tyt = bt >> 4;
        int cx = tid & 63, ry = tid >> 6;
        #pragma unroll
        for (int rr = 0; rr < 16; ++rr) {
            int r = ry + rr * 4;
            tile[r][cx] = Wmod[(tyt*64 + r) * 1024 + txt*64 + cx];
        }
        __syncthreads();
        #pragma unroll
        for (int rr = 0; rr < 16; ++rr) {
            int r = ry + rr * 4;
            wbT[(txt*64 + r) * 512 + tyt*64 + cx] = f2bf(tile[cx][r]);
        }
    } else if (bid < 1153) {
        int t = (bid - 129) * 256 + tid;
        const float4* s = reinterpret_cast<const float4*>(cin) + (size_t)t * 2;
        float4 a = s[0], b = s[1];
        uint4 o;
        o.x = pk2(f2bf(silu_f(a.x)), f2bf(silu_f(a.y)));
        o.y = pk2(f2bf(silu_f(a.z)), f2bf(silu_f(a.w)));
        o.z = pk2(f2bf(silu_f(b.x)), f2bf(silu_f(b.y)));
        o.w = pk2(f2bf(silu_f(b.z)), f2bf(silu_f(b.w)));
        *reinterpret_cast<uint4*>(cb + (size_t)t * 8) = o;
    } else if (bid < 1169) {
        // wgb[(kk*64 + l)*8 .. +7] = bf16 B-fragment (lane l, k-slab kk)
        int kk = bid - 1153;
        if (tid < 64) {
            int l = tid;
            int col = l & 15, q = l >> 4;
            bool bvalid = col < 9;
            int cheb = col / 3, oo = col - cheb * 3;
            unsigned short t[8];
            #pragma unroll
            for (int j = 0; j < 8; ++j) {
                int c = kk * 32 + q * 8 + j;
                float v = bvalid ? Wg[cheb * 1536 + c * 3 + oo] : 0.0f;
                t[j] = f2bf(v);
            }
            uint4 uv;
            uv.x = pk2(t[0], t[1]); uv.y = pk2(t[2], t[3]);
            uv.z = pk2(t[4], t[5]); uv.w = pk2(t[6], t[7]);
            *reinterpret_cast<uint4*>(wgb + ((size_t)kk * 64 + l) * 8) = uv;
        }
    } else {
        // Wtg[r*512 + i] with i = (c&7)*64 + (c>>3)  ->  c = ((i&63)<<3) | (i>>6)
        for (int idx = tid; idx < 4608; idx += 256) {
            int r = idx >> 9, i = idx & 511;
            int c = ((i & 63) << 3) | (i >> 6);
            Wtg[idx] = Wg[(r / 3) * 1536 + c * 3 + (r % 3)];
        }
    }
}

// ---------------------------------------------------------------------------
// Kernel 2: H[4096][1024] = cb[4096][512] @ wbT^T + b_mod   (MFMA bf16)
// ---------------------------------------------------------------------------
__global__ __launch_bounds__(256) void gemm_kernel(
        const unsigned short* __restrict__ cb, const unsigned short* __restrict__ wbT,
        const float* __restrict__ b_mod, float* __restrict__ H) {
    int w = threadIdx.x >> 6, l = threadIdx.x & 63;
    int lr = l & 15, lk = (l >> 4) * 8;
    int rowbase = blockIdx.y * 128 + w * 32;
    int colbase = blockIdx.x * 64;
    f32x4 acc[2][4] = {};
    for (int kk = 0; kk < 16; ++kk) {
        int k = kk * 32 + lk;
        short8 a0 = *reinterpret_cast<const short8*>(cb + (size_t)(rowbase + lr) * 512 + k);
        short8 a1 = *reinterpret_cast<const short8*>(cb + (size_t)(rowbase + 16 + lr) * 512 + k);
        #pragma unroll
        for (int j = 0; j < 4; ++j) {
            short8 bv = *reinterpret_cast<const short8*>(wbT + (size_t)(colbase + j*16 + lr) * 512 + k);
            acc[0][j] = __builtin_amdgcn_mfma_f32_16x16x32_bf16(a0, bv, acc[0][j], 0, 0, 0);
            acc[1][j] = __builtin_amdgcn_mfma_f32_16x16x32_bf16(a1, bv, acc[1][j], 0, 0, 0);
        }
    }
    #pragma unroll
    for (int j = 0; j < 4; ++j) {
        int col = colbase + j * 16 + lr;
        float bm = b_mod[col];
        #pragma unroll
        for (int i = 0; i < 2; ++i) {
            int row0 = rowbase + i * 16 + (l >> 4) * 4;
            #pragma unroll
            for (int r = 0; r < 4; ++r)
                H[(size_t)(row0 + r) * 1024 + col] = acc[i][j][r] + bm;
        }
    }
}

// ---------------------------------------------------------------------------
// Kernel 3 (mainA): streaming MFMA over flattened rows g = b*17 + n.
// 2 waves x 16 rows = 32 rows/block, grid 2176 -> ALL blocks co-resident
// (<=10 blocks/CU capacity at 128 thr, VGPR<=102): zero tail, ~17 waves/CU.
// Short dependent chain: (1+s)*x = fmaf(s,x,x); pack via v_cvt_pk_bf16_f32.
// Writes Gw[g][12]: cols 0-8 = G, 9 = mu, 10 = rstd.
// ---------------------------------------------------------------------------
__global__ __launch_bounds__(128, 5) void mainA_kernel(
        const float* __restrict__ x, const unsigned short* __restrict__ wgb,
        const float* __restrict__ H, float* __restrict__ Gw) {
    int tid = threadIdx.x, w = tid >> 6, l = tid & 63;
    int col = l & 15, q = l >> 4;
    int R0 = blockIdx.x * 32;
    int myrow = R0 + w * 16 + col;
    int b = myrow / 17;
    const float* xrow = x + (size_t)myrow * 512 + q * 8;
    const float* srow = H + (size_t)b * 1024 + 512 + q * 8;

    short8 bf[16];
    #pragma unroll
    for (int kk = 0; kk < 16; ++kk)
        bf[kk] = *reinterpret_cast<const short8*>(wgb + ((size_t)kk * 64 + l) * 8);

    float sum = 0.0f, sumsq = 0.0f;
    f32x4 acc = {0.f, 0.f, 0.f, 0.f};
    #pragma unroll
    for (int kk = 0; kk < 16; ++kk) {
        float4 xa = *reinterpret_cast<const float4*>(xrow + kk * 32);
        float4 xb = *reinterpret_cast<const float4*>(xrow + kk * 32 + 4);
        float4 sa = *reinterpret_cast<const float4*>(srow + kk * 32);
        float4 sb = *reinterpret_cast<const float4*>(srow + kk * 32 + 4);
        sum  += xa.x + xa.y + xa.z + xa.w + xb.x + xb.y + xb.z + xb.w;
        sumsq = fmaf(xa.x, xa.x, sumsq); sumsq = fmaf(xa.y, xa.y, sumsq);
        sumsq = fmaf(xa.z, xa.z, sumsq); sumsq = fmaf(xa.w, xa.w, sumsq);
        sumsq = fmaf(xb.x, xb.x, sumsq); sumsq = fmaf(xb.y, xb.y, sumsq);
        sumsq = fmaf(xb.z, xb.z, sumsq); sumsq = fmaf(xb.w, xb.w, sumsq);
        // modulated A-fragment: (1+s)*x = fmaf(s,x,x); RNE pack (v_cvt_pk_bf16_f32)
        float2 m0 = make_float2(fmaf(sa.x, xa.x, xa.x), fmaf(sa.y, xa.y, xa.y));
        float2 m1 = make_float2(fmaf(sa.z, xa.z, xa.z), fmaf(sa.w, xa.w, xa.w));
        float2 m2 = make_float2(fmaf(sb.x, xb.x, xb.x), fmaf(sb.y, xb.y, xb.y));
        float2 m3 = make_float2(fmaf(sb.z, xb.z, xb.z), fmaf(sb.w, xb.w, xb.w));
        __hip_bfloat162 c0 = __float22bfloat162_rn(m0);
        __hip_bfloat162 c1 = __float22bfloat162_rn(m1);
        __hip_bfloat162 c2 = __float22bfloat162_rn(m2);
        __hip_bfloat162 c3 = __float22bfloat162_rn(m3);
        uint4 uv;
        uv.x = *reinterpret_cast<unsigned int*>(&c0);
        uv.y = *reinterpret_cast<unsigned int*>(&c1);
        uv.z = *reinterpret_cast<unsigned int*>(&c2);
        uv.w = *reinterpret_cast<unsigned int*>(&c3);
        short8 av = *reinterpret_cast<short8*>(&uv);
        acc = __builtin_amdgcn_mfma_f32_16x16x32_bf16(av, bf[kk], acc, 0, 0, 0);
    }

    // combine raw-x stats across the 4 q-groups holding the same row
    sum   += __shfl_xor(sum, 16);   sum   += __shfl_xor(sum, 32);
    sumsq += __shfl_xor(sumsq, 16); sumsq += __shfl_xor(sumsq, 32);
    float mu  = sum * (1.0f / 512.0f);
    float var = sumsq * (1.0f / 512.0f) - mu * mu;
    float rstd = rsqrtf(var + 1e-6f);

    size_t gbase = (size_t)(R0 + w * 16);
    if (col < 9) {
        #pragma unroll
        for (int r = 0; r < 4; ++r)
            Gw[(gbase + q * 4 + r) * 12 + col] = acc[r];
    }
    if (l < 16) {
        Gw[(gbase + l) * 12 + 9]  = mu;
        Gw[(gbase + l) * 12 + 10] = rstd;
    }
}

// ---------------------------------------------------------------------------
// Kernel 4 (combine): per batch (wave): S = shift@Wt, CS = (1+scale)@Wt,
// P = rstd*(G - mu*CS), A_k = P_k + S_k, Q = L@A2,
// out = A0 - A2 + L@(A1 + 2Q) + bg.
// ---------------------------------------------------------------------------
__global__ __launch_bounds__(512) void combine_kernel(
        const float* __restrict__ H, const float* __restrict__ Wtg,
        const float* __restrict__ Lw, const float* __restrict__ bg,
        const float* __restrict__ Gw, float* __restrict__ out) {
    __shared__ float Wt_t[9][512];     // pre-swizzled: row r, slot (c&7)*64+(c>>3)
    __shared__ float L_s[17][20];
    __shared__ float A2_s[8][17][3];
    __shared__ float B1_s[8][17][3];

    int tid = threadIdx.x, w = tid >> 6, l = tid & 63;

    #pragma unroll
    for (int r = 0; r < 9; ++r)
        Wt_t[r][tid] = Wtg[r * 512 + tid];
    if (tid < 289) L_s[tid / 17][tid % 17] = Lw[tid];
    __syncthreads();

    int b = blockIdx.x * 8 + w;
    const float* hrow = H + (size_t)b * 1024;
    float4 h0 = *reinterpret_cast<const float4*>(hrow + 8 * l);
    float4 h1 = *reinterpret_cast<const float4*>(hrow + 8 * l + 4);
    float4 h2 = *reinterpret_cast<const float4*>(hrow + 512 + 8 * l);
    float4 h3 = *reinterpret_cast<const float4*>(hrow + 512 + 8 * l + 4);
    float shj[8] = {h0.x, h0.y, h0.z, h0.w, h1.x, h1.y, h1.z, h1.w};
    float scj[8] = {1.f+h2.x, 1.f+h2.y, 1.f+h2.z, 1.f+h2.w,
                    1.f+h3.x, 1.f+h3.y, 1.f+h3.z, 1.f+h3.w};

    float sA[9], cA[9];
    #pragma unroll
    for (int r = 0; r < 9; ++r) {
        float s = 0.0f, cs = 0.0f;
        #pragma unroll
        for (int j = 0; j < 8; ++j) {
            float wv = Wt_t[r][j * 64 + l];
            s  = fmaf(shj[j], wv, s);
            cs = fmaf(scj[j], wv, cs);
        }
        sA[r] = s; cA[r] = cs;
    }
    #pragma unroll
    for (int m = 1; m < 64; m <<= 1) {
        #pragma unroll
        for (int r = 0; r < 9; ++r) {
            sA[r] += __shfl_xor(sA[r], m);
            cA[r] += __shfl_xor(cA[r], m);
        }
    }

    int lc = l < 51 ? l : 50;
    int n = lc / 3, o = lc - n * 3;
    float S0 = sel3(sA[0], sA[1], sA[2], o);
    float S1 = sel3(sA[3], sA[4], sA[5], o);
    float S2 = sel3(sA[6], sA[7], sA[8], o);
    float C0 = sel3(cA[0], cA[1], cA[2], o);
    float C1 = sel3(cA[3], cA[4], cA[5], o);
    float C2 = sel3(cA[6], cA[7], cA[8], o);

    const float* grow = Gw + (size_t)(b * 17 + n) * 12;
    float g0 = grow[o], g1 = grow[3 + o], g2 = grow[6 + o];
    float mu = grow[9], rstd = grow[10];
    float A0 = rstd * (g0 - mu * C0) + S0;
    float A1 = rstd * (g1 - mu * C1) + S1;
    float A2 = rstd * (g2 - mu * C2) + S2;

    A2_s[w][n][o] = A2;
    __syncthreads();
    float Qv = 0.0f;
    #pragma unroll
    for (int m = 0; m < 17; ++m) Qv = fmaf(L_s[n][m], A2_s[w][m][o], Qv);
    B1_s[w][n][o] = A1 + 2.0f * Qv;
    __syncthreads();
    float rv = A0 - A2 + bg[o];
    #pragma unroll
    for (int m = 0; m < 17; ++m) rv = fmaf(L_s[n][m], B1_s[w][m][o], rv);
    if (l < 51) out[(size_t)b * 51 + lc] = rv;
}

// ---------------------------------------------------------------------------
extern "C" void kernel_launch(void* const* d_in, const int* in_sizes, int n_in,
                              void* d_out, int out_size, void* d_ws, size_t ws_size,
                              hipStream_t stream) {
    const float* x     = (const float*)d_in[0];
    const float* adj   = (const float*)d_in[1];
    const float* c     = (const float*)d_in[2];
    const float* W_mod = (const float*)d_in[3];
    const float* b_mod = (const float*)d_in[4];
    const float* Wg    = (const float*)d_in[5];
    const float* bg    = (const float*)d_in[6];
    float* out = (float*)d_out;

    // workspace: cb 4MB @0 | wbT @4MB | H @5MB | Lw @21MB | Gw @22MB (3.3MB)
    //            wgb @32MB (16KB) | Wtg @33MB (18KB)     (d_ws is ~544MB)
    unsigned short* cb  = (unsigned short*)d_ws;
    unsigned short* wbT = (unsigned short*)((char*)d_ws + (4u << 20));
    float*          H   = (float*)((char*)d_ws + (5u << 20));
    float*          Lw  = (float*)((char*)d_ws + (21u << 20));
    float*          Gw  = (float*)((char*)d_ws + (22u << 20));
    unsigned short* wgb = (unsigned short*)((char*)d_ws + (32u << 20));
    float*          Wtg = (float*)((char*)d_ws + (33u << 20));

    prep_kernel<<<1170, 256, 0, stream>>>(c, W_mod, adj, Wg, cb, wbT, Lw, wgb, Wtg);
    gemm_kernel<<<dim3(16, 32), 256, 0, stream>>>(cb, wbT, b_mod, H);
    mainA_kernel<<<2176, 128, 0, stream>>>(x, wgb, H, Gw);
    combine_kernel<<<512, 512, 0, stream>>>(H, Wtg, Lw, bg, Gw, out);
}